// Round 10
// baseline (79.800 us; speedup 1.0000x reference)
//
#include <hip/hip_runtime.h>
#include <math.h>

// Chamfer distance via MFMA, fp16 quantized / fp32 accumulate.
// K-packing: A_row = (-2ax,-2ay,-2az, 1, sqa, 0,0,0), B_col = (bx,by,bz, sqb, 1, ...)
// => MFMA dot = sqa + sqb - 2 a.b = full squared distance (from quantized coords).
//
// R19 vs R18: R18 failed correctness (absmax 192). Root causes, all raw-asm
// hazards the compiler used to handle: (1) v67/v71 (B K6/K7) never written ->
// garbage f16, NaN/Inf poisons columns via 0*Inf; (2) srcB overwrite race:
// next step's ds_read wrote v[64:65] while the in-flight MFMAs were still
// reading them across their 16 passes; (3) thin D-read pad. Fix: E/O
// double-buffered B operand regs (E=v[64:71], O=v[72:79]) so ds_read never
// touches regs an in-flight MFMA reads; K4=1.0 / K6,K7=0 constants written
// ONCE in the prologue for both pairs; fold pad = 4x s_nop 7 (~36 cyc).
// Parity: PRO(step0,E) + 31x{STEP_O,STEP_E} (steps 1..62) + STEP_O(63) + FOLD.
// Theory under test (R17 counters: VGPR_Count=60 proves AGPR split +
// marshaling): keep MFMA D-tuples inside one asm block per step -- fold the
// PREVIOUS step's D with 16x v_min3 in the same block, D lives only in
// hardcoded scratch v[32:63]; nothing for the allocator to marshal.
// Macro-structure = R13/R17: 2 dispatches (memset4B + fused kernel), full B
// cloud packed in-kernel to 128KB LDS, BLK=1024 = 16 waves = 4/SIMD,
// waves = 4 row-groups x 4 B-quarters, no grid.sync.

typedef _Float16 half8    __attribute__((ext_vector_type(8)));
typedef float    floatx16 __attribute__((ext_vector_type(16)));

constexpr int NPTS = 16384;    // padded cloud size (128 KB LDS), fixed problem
constexpr int ROWS = 128;      // A-rows per block (4 row-groups * 32)
constexpr int BLK  = 1024;     // 16 waves = 4/SIMD at 1 block/CU

// ---- pack one point into an f16 fragment (x,y,z,|p|^2) ----
__device__ __forceinline__ uint2 pack_point(const float* __restrict__ P, int j)
{
    float x = P[3*j], y = P[3*j+1], z = P[3*j+2];
    _Float16 hx = (_Float16)x, hy = (_Float16)y, hz = (_Float16)z;
    float qx = (float)hx, qy = (float)hy, qz = (float)hz;
    _Float16 hw = (_Float16)(qx*qx + qy*qy + qz*qz);
    union { _Float16 h[4]; uint2 u; } p;
    p.h[0] = hx; p.h[1] = hy; p.h[2] = hz; p.h[3] = hw;
    return p.u;
}

// Scratch: D0=v[32:47], D1=v[48:63]; B pairs E=v[64:71], O=v[72:79].
#define CLB "v32","v33","v34","v35","v36","v37","v38","v39", \
            "v40","v41","v42","v43","v44","v45","v46","v47", \
            "v48","v49","v50","v51","v52","v53","v54","v55", \
            "v56","v57","v58","v59","v60","v61","v62","v63", \
            "v64","v65","v66","v67","v68","v69","v70","v71", \
            "v72","v73","v74","v75","v76","v77","v78","v79"

// Prologue: init BOTH B-pair constant halves (K4=1.0h,K5=0 | K6=K7=0),
// load step 0 into E, issue step 0 MFMAs.
#define PRO_ASM \
    "ds_read_b64 v[64:65], %0\n\t" \
    "ds_read_b64 v[68:69], %0 offset:256\n\t" \
    "v_mov_b32 v66, 0x3c00\n\t" \
    "v_mov_b32 v67, 0\n\t" \
    "v_mov_b32 v70, 0x3c00\n\t" \
    "v_mov_b32 v71, 0\n\t" \
    "v_mov_b32 v74, 0x3c00\n\t" \
    "v_mov_b32 v75, 0\n\t" \
    "v_mov_b32 v78, 0x3c00\n\t" \
    "v_mov_b32 v79, 0\n\t" \
    "v_add_u32 %0, 512, %0\n\t" \
    "s_waitcnt lgkmcnt(0)\n\t" \
    "v_mfma_f32_32x32x16_f16 v[32:47], %1, v[64:67], %2\n\t" \
    "v_mfma_f32_32x32x16_f16 v[48:63], %1, v[68:71], %2"

#define FOLD16 \
    "v_min3_f32 %1, %1, v32, v48\n\t" \
    "v_min3_f32 %2, %2, v33, v49\n\t" \
    "v_min3_f32 %3, %3, v34, v50\n\t" \
    "v_min3_f32 %4, %4, v35, v51\n\t" \
    "v_min3_f32 %5, %5, v36, v52\n\t" \
    "v_min3_f32 %6, %6, v37, v53\n\t" \
    "v_min3_f32 %7, %7, v38, v54\n\t" \
    "v_min3_f32 %8, %8, v39, v55\n\t" \
    "v_min3_f32 %9, %9, v40, v56\n\t" \
    "v_min3_f32 %10, %10, v41, v57\n\t" \
    "v_min3_f32 %11, %11, v42, v58\n\t" \
    "v_min3_f32 %12, %12, v43, v59\n\t" \
    "v_min3_f32 %13, %13, v44, v60\n\t" \
    "v_min3_f32 %14, %14, v45, v61\n\t" \
    "v_min3_f32 %15, %15, v46, v62\n\t" \
    "v_min3_f32 %16, %16, v47, v63\n\t"

// Step, O-phase: load into O pair (in-flight MFMAs read E), fold prev D,
// wait loads, MFMA from O. E-phase: mirrored.
#define STEP_O_ASM \
    "ds_read_b64 v[72:73], %0\n\t" \
    "ds_read_b64 v[76:77], %0 offset:256\n\t" \
    "v_add_u32 %0, 512, %0\n\t" \
    "s_nop 7\n\t" "s_nop 7\n\t" "s_nop 7\n\t" "s_nop 7\n\t" \
    FOLD16 \
    "s_waitcnt lgkmcnt(0)\n\t" \
    "v_mfma_f32_32x32x16_f16 v[32:47], %17, v[72:75], %18\n\t" \
    "v_mfma_f32_32x32x16_f16 v[48:63], %17, v[76:79], %18"

#define STEP_E_ASM \
    "ds_read_b64 v[64:65], %0\n\t" \
    "ds_read_b64 v[68:69], %0 offset:256\n\t" \
    "v_add_u32 %0, 512, %0\n\t" \
    "s_nop 7\n\t" "s_nop 7\n\t" "s_nop 7\n\t" "s_nop 7\n\t" \
    FOLD16 \
    "s_waitcnt lgkmcnt(0)\n\t" \
    "v_mfma_f32_32x32x16_f16 v[32:47], %17, v[64:67], %18\n\t" \
    "v_mfma_f32_32x32x16_f16 v[48:63], %17, v[68:71], %18"

// Final fold of the last step's D (pad well past MFMA latency).
#define FIN_ASM \
    "s_nop 7\n\t" "s_nop 7\n\t" "s_nop 7\n\t" "s_nop 7\n\t" \
    "v_min3_f32 %0, %0, v32, v48\n\t" \
    "v_min3_f32 %1, %1, v33, v49\n\t" \
    "v_min3_f32 %2, %2, v34, v50\n\t" \
    "v_min3_f32 %3, %3, v35, v51\n\t" \
    "v_min3_f32 %4, %4, v36, v52\n\t" \
    "v_min3_f32 %5, %5, v37, v53\n\t" \
    "v_min3_f32 %6, %6, v38, v54\n\t" \
    "v_min3_f32 %7, %7, v39, v55\n\t" \
    "v_min3_f32 %8, %8, v40, v56\n\t" \
    "v_min3_f32 %9, %9, v41, v57\n\t" \
    "v_min3_f32 %10, %10, v42, v58\n\t" \
    "v_min3_f32 %11, %11, v43, v59\n\t" \
    "v_min3_f32 %12, %12, v44, v60\n\t" \
    "v_min3_f32 %13, %13, v45, v61\n\t" \
    "v_min3_f32 %14, %14, v46, v62\n\t" \
    "v_min3_f32 %15, %15, v47, v63"

#define RM_OUTS "+v"(rm0), "+v"(rm1), "+v"(rm2), "+v"(rm3), \
                "+v"(rm4), "+v"(rm5), "+v"(rm6), "+v"(rm7), \
                "+v"(rm8), "+v"(rm9), "+v"(rm10), "+v"(rm11), \
                "+v"(rm12), "+v"(rm13), "+v"(rm14), "+v"(rm15)

// One fused kernel: pack B->LDS, pack own A-rows->regs, sweep, reduce, atomicAdd.
__global__ __launch_bounds__(BLK, 4) void chamfer_all_kernel(
    const float* __restrict__ P1, const float* __restrict__ P2,
    float* __restrict__ out, int n1, int n2)
{
    __shared__ uint2 sB[NPTS];            // packed B cloud
    __shared__ float sRowMin[4][ROWS];    // per-B-quarter row mins
    __shared__ float sRed[ROWS];          // final per-row sqrt'd values

    const int dir   = blockIdx.z;
    const float* PA = dir == 0 ? P1 : P2;
    const float* PB = dir == 0 ? P2 : P1;
    const int nA    = dir == 0 ? n1 : n2;
    const int nB    = dir == 0 ? n2 : n1;

    const int tid  = threadIdx.x;
    const int wave = tid >> 6;
    const int lane = tid & 63;
    const int n    = lane & 31;
    const int g    = lane >> 5;
    const bool g0  = (g == 0);
    const int wr   = wave & 3;        // row-group: rows wr*32 .. wr*32+31
    const int wq   = wave >> 2;       // B-quarter index

    // ---- pack the FULL B cloud into LDS (reads are L2-resident, 192 KB) ----
    for (int j = tid; j < NPTS; j += BLK) {
        int jj = j < nB ? j : nB - 1;        // pad with dup of last point
        sB[j] = pack_point(PB, jj);
    }

    // ---- A fragment: pack own row directly from fp32 points ----
    const _Float16 h0 = (_Float16)0.0f;
    half8 af;
    {
        int arow = blockIdx.x * ROWS + wr * 32 + n;
        int j = arow < nA ? arow : nA - 1;
        union { uint2 u; _Float16 h[4]; } au; au.u = pack_point(PA, j);
        const _Float16 m2 = (_Float16)(-2.0f);
        af[0] = g0 ? (_Float16)(au.h[0] * m2) : h0;
        af[1] = g0 ? (_Float16)(au.h[1] * m2) : h0;
        af[2] = g0 ? (_Float16)(au.h[2] * m2) : h0;
        af[3] = g0 ? (_Float16)1.0f : h0;
        af[4] = g0 ? au.h[3] : h0;
        af[5] = h0; af[6] = h0; af[7] = h0;
    }

    __syncthreads();

    floatx16 zacc;
#pragma unroll
    for (int r = 0; r < 16; ++r) zacc[r] = 0.0f;

    float rm0 = 1e30f, rm1 = 1e30f, rm2 = 1e30f, rm3 = 1e30f,
          rm4 = 1e30f, rm5 = 1e30f, rm6 = 1e30f, rm7 = 1e30f,
          rm8 = 1e30f, rm9 = 1e30f, rm10 = 1e30f, rm11 = 1e30f,
          rm12 = 1e30f, rm13 = 1e30f, rm14 = 1e30f, rm15 = 1e30f;

    // LDS byte address of this wave's quarter (g0/g1 broadcast same addr).
    constexpr int QLEN = NPTS >> 2;            // 4096 points
    unsigned aaddr = (unsigned)(size_t)(sB + wq * QLEN + n);

    // ---- sweep own B-quarter: 64 steps (step0 PRO + 31x{O,E} + tail O) ----
    asm volatile(PRO_ASM : "+v"(aaddr) : "v"(af), "v"(zacc) : CLB, "memory");
    for (int it = 0; it < 31; ++it) {
        asm volatile(STEP_O_ASM
            : "+v"(aaddr), RM_OUTS : "v"(af), "v"(zacc) : CLB, "memory");
        asm volatile(STEP_E_ASM
            : "+v"(aaddr), RM_OUTS : "v"(af), "v"(zacc) : CLB, "memory");
    }
    asm volatile(STEP_O_ASM
        : "+v"(aaddr), RM_OUTS : "v"(af), "v"(zacc) : CLB, "memory");
    asm volatile(FIN_ASM : RM_OUTS : : CLB);

    float rowmin[16] = { rm0, rm1, rm2, rm3, rm4, rm5, rm6, rm7,
                         rm8, rm9, rm10, rm11, rm12, rm13, rm14, rm15 };

    // ---- reduce across the 32 cols (xor-shuffle within n-group) ----
#pragma unroll
    for (int mask = 1; mask <= 16; mask <<= 1)
#pragma unroll
        for (int r = 0; r < 16; ++r)
            rowmin[r] = fminf(rowmin[r], __shfl_xor(rowmin[r], mask));

    if (n == 0) {
#pragma unroll
        for (int r = 0; r < 16; ++r) {
            int rr = wr * 32 + g * 4 + ((r & 3) + 8 * (r >> 2));   // C/D row map
            sRowMin[wq][rr] = rowmin[r];
        }
    }
    __syncthreads();

    // ---- combine quarters, sqrt, block-sum, one atomicAdd ----
    if (tid < ROWS) {
        float m = fminf(fminf(sRowMin[0][tid], sRowMin[1][tid]),
                        fminf(sRowMin[2][tid], sRowMin[3][tid]));
        int grow = blockIdx.x * ROWS + tid;
        sRed[tid] = (grow < nA) ? sqrtf(fmaxf(m, 0.0f)) : 0.0f;
    }
    __syncthreads();

    if (tid < 64) {
        float v = sRed[tid] + sRed[tid + 64];
#pragma unroll
        for (int mask = 1; mask <= 32; mask <<= 1)
            v += __shfl_xor(v, mask);
        if (tid == 0) atomicAdd(out, v);
    }
}

extern "C" void kernel_launch(void* const* d_in, const int* in_sizes, int n_in,
                              void* d_out, int out_size, void* d_ws, size_t ws_size,
                              hipStream_t stream) {
    const float* P1 = (const float*)d_in[0];
    const float* P2 = (const float*)d_in[1];
    const int n1 = in_sizes[0] / 3;   // 16384
    const int n2 = in_sizes[1] / 3;   // 16384
    float* out = (float*)d_out;

    hipMemsetAsync(out, 0, sizeof(float), stream);   // capture-safe

    dim3 grid(NPTS / ROWS, 1, 2);                    // 256 blocks = exactly 1/CU
    chamfer_all_kernel<<<grid, BLK, 0, stream>>>(P1, P2, out, n1, n2);
}